// Round 1
// baseline (1058.224 us; speedup 1.0000x reference)
//
#include <hip/hip_runtime.h>
#include <math.h>

#define N_NODES 50000
#define N_EDGES 800000
#define F_INPUT 128
#define HID 64
#define NHEAD 3
#define NGRAPH 50
#define D1 192   // NHEAD*HID
#define D2 384   // 2*D1 (fs|fd)

// ---------------- graph-structure kernels (run once per call) ----------------

__global__ void zero_int_kernel(int* __restrict__ p, int n) {
  int i = blockIdx.x * blockDim.x + threadIdx.x;
  if (i < n) p[i] = 0;
}

__global__ void hist_kernel(const int* __restrict__ dst, int* __restrict__ counts, int e) {
  int i = blockIdx.x * blockDim.x + threadIdx.x;
  if (i < e) atomicAdd(&counts[dst[i]], 1);
}

// single-block hierarchical scan: indptr[0]=0; indptr[i+1]=sum(counts[0..i])
__global__ __launch_bounds__(1024) void scan_kernel(const int* __restrict__ counts,
                                                    int* __restrict__ indptr, int n) {
  __shared__ int wtot[16];
  __shared__ int s_carry;
  int tid = threadIdx.x;
  int lane = tid & 63, wid = tid >> 6;
  if (tid == 0) { s_carry = 0; indptr[0] = 0; }
  __syncthreads();
  for (int base = 0; base < n; base += 1024) {
    int i = base + tid;
    int x = (i < n) ? counts[i] : 0;
    // wave inclusive scan
    #pragma unroll
    for (int off = 1; off < 64; off <<= 1) {
      int t = __shfl_up(x, off, 64);
      if (lane >= off) x += t;
    }
    if (lane == 63) wtot[wid] = x;
    __syncthreads();                       // (1)
    if (wid == 0 && lane < 16) {
      int w = wtot[lane];
      #pragma unroll
      for (int off = 1; off < 16; off <<= 1) {
        int t = __shfl_up(w, off, 16);
        if (lane >= off) w += t;
      }
      wtot[lane] = w;                      // inclusive scan of wave totals
    }
    __syncthreads();                       // (2)
    int waveoff = (wid > 0) ? wtot[wid - 1] : 0;
    int carry = s_carry;
    if (i < n) indptr[i + 1] = carry + waveoff + x;
    __syncthreads();                       // (3)
    if (tid == 1023) s_carry = carry + wtot[15];
    // next iteration's barrier (1) orders this write before any read
  }
}

__global__ void initcur_kernel(const int* __restrict__ indptr, int* __restrict__ cursor, int n) {
  int i = blockIdx.x * blockDim.x + threadIdx.x;
  if (i < n) cursor[i] = indptr[i];
}

__global__ void scatter_kernel(const int* __restrict__ src, const int* __restrict__ dst,
                               int* __restrict__ cursor, int* __restrict__ ssrc, int e) {
  int i = blockIdx.x * blockDim.x + threadIdx.x;
  if (i < e) {
    int pos = atomicAdd(&cursor[dst[i]], 1);
    ssrc[pos] = src[i];
  }
}

// ---------------- fused src/dst feature GEMM: C[M,384] = A[M,K] @ [Wsrc|Wdst] + [bsrc|bdst]

__global__ __launch_bounds__(256)
void gemm_kernel(const float* __restrict__ A, int M, int K,
                 const float* __restrict__ Wsrc, const float* __restrict__ bsrc,
                 const float* __restrict__ Wdst, const float* __restrict__ bdst,
                 float* __restrict__ C) {
  const int BM = 64, BN = 64, BK = 32;
  __shared__ float As[BK][BM + 8];   // 72-float rows: keeps 16B align, spreads banks
  __shared__ float Bs[BK][BN];
  int tid = threadIdx.x;
  int m0 = blockIdx.x * BM;
  int n0 = blockIdx.y * BN;
  const float* W; const float* bias; int nc0;
  if (n0 < D1) { W = Wsrc; bias = bsrc; nc0 = n0; }
  else         { W = Wdst; bias = bdst; nc0 = n0 - D1; }
  int tx = tid & 15, ty = tid >> 4;
  float acc[4][4] = {};
  for (int k0 = 0; k0 < K; k0 += BK) {
    #pragma unroll
    for (int t = 0; t < 2; ++t) {                  // A tile 64x32, transposed into LDS
      int f = tid + t * 256;
      int m = f & 63, kq = f >> 6;                 // kq 0..7
      float4 v = make_float4(0.f, 0.f, 0.f, 0.f);
      int gm = m0 + m;
      if (gm < M) v = *(const float4*)(A + (size_t)gm * K + (k0 + kq * 4));
      As[kq * 4 + 0][m] = v.x;
      As[kq * 4 + 1][m] = v.y;
      As[kq * 4 + 2][m] = v.z;
      As[kq * 4 + 3][m] = v.w;
    }
    #pragma unroll
    for (int t = 0; t < 2; ++t) {                  // B tile 32x64
      int f = tid + t * 256;
      int n4 = f & 15, kk = f >> 4;                // kk 0..31
      *(float4*)&Bs[kk][n4 * 4] =
          *(const float4*)(W + (size_t)(k0 + kk) * D1 + nc0 + n4 * 4);
    }
    __syncthreads();
    #pragma unroll
    for (int k = 0; k < BK; ++k) {
      float4 av = *(const float4*)&As[k][ty * 4];
      float4 bv = *(const float4*)&Bs[k][tx * 4];
      float ar[4] = {av.x, av.y, av.z, av.w};
      float br[4] = {bv.x, bv.y, bv.z, bv.w};
      #pragma unroll
      for (int r = 0; r < 4; ++r)
        #pragma unroll
        for (int c = 0; c < 4; ++c)
          acc[r][c] = fmaf(ar[r], br[c], acc[r][c]);
    }
    __syncthreads();
  }
  float4 bv = *(const float4*)(bias + nc0 + tx * 4);
  float bb[4] = {bv.x, bv.y, bv.z, bv.w};
  #pragma unroll
  for (int r = 0; r < 4; ++r) {
    int gm = m0 + ty * 4 + r;
    if (gm < M) {
      float4 o;
      o.x = acc[r][0] + bb[0];
      o.y = acc[r][1] + bb[1];
      o.z = acc[r][2] + bb[2];
      o.w = acc[r][3] + bb[3];
      *(float4*)(C + (size_t)gm * D2 + n0 + tx * 4) = o;
    }
  }
}

// ---------------- fused edge phase: one wave per dst node, online softmax ----------------

__device__ __forceinline__ float wredsum(float v) {
  #pragma unroll
  for (int off = 32; off > 0; off >>= 1) v += __shfl_xor(v, off, 64);
  return v;
}

template <int LAST>
__global__ __launch_bounds__(256)
void edge_kernel(const float* __restrict__ fsfd, const int* __restrict__ indptr,
                 const int* __restrict__ ssrc, const float* __restrict__ attn,
                 float* __restrict__ out) {
  int wave = (blockIdx.x * blockDim.x + threadIdx.x) >> 6;
  if (wave >= N_NODES) return;
  int lane = threadIdx.x & 63;
  int node = wave;
  const float* fdp = fsfd + (size_t)node * D2 + D1;
  float fd0 = fdp[lane], fd1 = fdp[64 + lane], fd2 = fdp[128 + lane];
  float a0 = attn[lane], a1 = attn[64 + lane], a2 = attn[128 + lane];
  int beg = indptr[node], end = indptr[node + 1];
  float m0 = -INFINITY, m1 = -INFINITY, m2 = -INFINITY;
  float d0 = 0.f, d1 = 0.f, d2 = 0.f;
  float c0 = 0.f, c1 = 0.f, c2 = 0.f;
  for (int e = beg; e < end; ++e) {
    int s = ssrc[e];
    const float* fsp = fsfd + (size_t)s * D2;
    float f0 = fsp[lane], f1 = fsp[64 + lane], f2 = fsp[128 + lane];
    float t0 = f0 + fd0, t1 = f1 + fd1, t2 = f2 + fd2;
    t0 = t0 > 0.f ? t0 : 0.2f * t0;
    t1 = t1 > 0.f ? t1 : 0.2f * t1;
    t2 = t2 > 0.f ? t2 : 0.2f * t2;
    float l0 = wredsum(t0 * a0);
    float l1 = wredsum(t1 * a1);
    float l2 = wredsum(t2 * a2);
    {
      float mn = fmaxf(m0, l0); float sc = __expf(m0 - mn); float p = __expf(l0 - mn);
      d0 = d0 * sc + p; c0 = fmaf(p, f0, c0 * sc); m0 = mn;
    }
    {
      float mn = fmaxf(m1, l1); float sc = __expf(m1 - mn); float p = __expf(l1 - mn);
      d1 = d1 * sc + p; c1 = fmaf(p, f1, c1 * sc); m1 = mn;
    }
    {
      float mn = fmaxf(m2, l2); float sc = __expf(m2 - mn); float p = __expf(l2 - mn);
      d2 = d2 * sc + p; c2 = fmaf(p, f2, c2 * sc); m2 = mn;
    }
  }
  float r0 = d0 > 0.f ? c0 / d0 : 0.f;
  float r1 = d1 > 0.f ? c1 / d1 : 0.f;
  float r2 = d2 > 0.f ? c2 / d2 : 0.f;
  if (LAST) {
    out[(size_t)node * HID + lane] = (r0 + r1 + r2) * (1.f / 3.f);
  } else {
    out[(size_t)node * D1 + lane] = r0;
    out[(size_t)node * D1 + 64 + lane] = r1;
    out[(size_t)node * D1 + 128 + lane] = r2;
  }
}

// ---------------- per-graph mean pool + 3-layer MLP ----------------

__global__ __launch_bounds__(256)
void pool_mlp_kernel(const float* __restrict__ h, const int* __restrict__ gids,
                     const float* __restrict__ W1, const float* __restrict__ b1,
                     const float* __restrict__ W2, const float* __restrict__ b2,
                     const float* __restrict__ W3, const float* __restrict__ b3,
                     float* __restrict__ out) {
  int g = blockIdx.x;
  int tid = threadIdx.x;
  int lane = tid & 63, wid = tid >> 6;
  int lo, hi;
  { int l = 0, r = N_NODES; while (l < r) { int mid = (l + r) >> 1; if (gids[mid] < g) l = mid + 1; else r = mid; } lo = l; }
  { int l = 0, r = N_NODES; while (l < r) { int mid = (l + r) >> 1; if (gids[mid] < g + 1) l = mid + 1; else r = mid; } hi = l; }
  float s = 0.f;
  for (int i = lo + wid; i < hi; i += 4) s += h[(size_t)i * HID + lane];
  __shared__ float red[4][64];
  __shared__ float gv[64], o1[64], o2[32];
  red[wid][lane] = s;
  __syncthreads();
  if (tid < 64) {
    float tot = red[0][tid] + red[1][tid] + red[2][tid] + red[3][tid];
    float cnt = (float)(hi - lo);
    gv[tid] = tot / fmaxf(cnt, 1.f);
  }
  __syncthreads();
  if (tid < 64) {
    float t = b1[tid];
    for (int k = 0; k < 64; ++k) t = fmaf(gv[k], W1[k * 64 + tid], t);
    o1[tid] = t > 0.f ? t : 0.01f * t;
  }
  __syncthreads();
  if (tid < 32) {
    float t = b2[tid];
    for (int k = 0; k < 64; ++k) t = fmaf(o1[k], W2[k * 32 + tid], t);
    o2[tid] = t > 0.f ? t : 0.01f * t;
  }
  __syncthreads();
  if (tid < 2) {
    float t = b3[tid];
    for (int k = 0; k < 32; ++k) t = fmaf(o2[k], W3[k * 2 + tid], t);
    out[g * 2 + tid] = t > 0.f ? t : 0.01f * t;
  }
}

// ---------------- launch ----------------

extern "C" void kernel_launch(void* const* d_in, const int* in_sizes, int n_in,
                              void* d_out, int out_size, void* d_ws, size_t ws_size,
                              hipStream_t stream) {
  const float* x    = (const float*)d_in[0];
  const int*   src  = (const int*)d_in[1];
  const int*   dst  = (const int*)d_in[2];
  const int*   gids = (const int*)d_in[3];
  // d_in[4] = n_graphs (constant 50)
  const float* Wsrc1 = (const float*)d_in[5];
  const float* bsrc1 = (const float*)d_in[6];
  const float* Wdst1 = (const float*)d_in[7];
  const float* bdst1 = (const float*)d_in[8];
  const float* attn1 = (const float*)d_in[9];
  const float* Wsrc2 = (const float*)d_in[10];
  const float* bsrc2 = (const float*)d_in[11];
  const float* Wdst2 = (const float*)d_in[12];
  const float* bdst2 = (const float*)d_in[13];
  const float* attn2 = (const float*)d_in[14];
  const float* Wsrc3 = (const float*)d_in[15];
  const float* bsrc3 = (const float*)d_in[16];
  const float* Wdst3 = (const float*)d_in[17];
  const float* bdst3 = (const float*)d_in[18];
  const float* attn3 = (const float*)d_in[19];
  const float* W1 = (const float*)d_in[20];
  const float* b1 = (const float*)d_in[21];
  const float* W2 = (const float*)d_in[22];
  const float* b2 = (const float*)d_in[23];
  const float* W3 = (const float*)d_in[24];
  const float* b3 = (const float*)d_in[25];
  float* out = (float*)d_out;

  // workspace layout (~119 MB total)
  float* fsfd  = (float*)d_ws;                         // N*384 f32
  float* h     = fsfd + (size_t)N_NODES * D2;          // N*192 f32
  int* counts  = (int*)(h + (size_t)N_NODES * D1);     // N (reused as cursor)
  int* indptr  = counts + N_NODES;                     // N+1
  int* ssrc    = indptr + (N_NODES + 1);               // E

  // CSR by dst (graph identical across layers)
  zero_int_kernel<<<(N_NODES + 255) / 256, 256, 0, stream>>>(counts, N_NODES);
  hist_kernel<<<(N_EDGES + 255) / 256, 256, 0, stream>>>(dst, counts, N_EDGES);
  scan_kernel<<<1, 1024, 0, stream>>>(counts, indptr, N_NODES);
  initcur_kernel<<<(N_NODES + 255) / 256, 256, 0, stream>>>(indptr, counts, N_NODES);
  scatter_kernel<<<(N_EDGES + 255) / 256, 256, 0, stream>>>(src, dst, counts, ssrc, N_EDGES);

  dim3 ggrid((N_NODES + 63) / 64, D2 / 64);
  dim3 egrid((N_NODES + 3) / 4);

  gemm_kernel<<<ggrid, 256, 0, stream>>>(x, N_NODES, F_INPUT, Wsrc1, bsrc1, Wdst1, bdst1, fsfd);
  edge_kernel<0><<<egrid, 256, 0, stream>>>(fsfd, indptr, ssrc, attn1, h);

  gemm_kernel<<<ggrid, 256, 0, stream>>>(h, N_NODES, D1, Wsrc2, bsrc2, Wdst2, bdst2, fsfd);
  edge_kernel<0><<<egrid, 256, 0, stream>>>(fsfd, indptr, ssrc, attn2, h);

  gemm_kernel<<<ggrid, 256, 0, stream>>>(h, N_NODES, D1, Wsrc3, bsrc3, Wdst3, bdst3, fsfd);
  edge_kernel<1><<<egrid, 256, 0, stream>>>(fsfd, indptr, ssrc, attn3, h);

  pool_mlp_kernel<<<NGRAPH, 256, 0, stream>>>(h, gids, W1, b1, W2, b2, W3, b3, out);
}